// Round 7
// baseline (25.819 us; speedup 1.0000x reference)
//
#include <hip/hip_runtime.h>

// RoPE: x (B=8, S=16384, D=128) f32, cos/sin tables (16384, 64) f32,
// token_positions (16384,) i32. Interleaved pair layout:
// out[2i]   = cos[i]*x[2i] - sin[i]*x[2i+1]
// out[2i+1] = sin[i]*x[2i] + cos[i]*x[2i+1]
//
// Block-local 4x MLP: each block owns a contiguous 1024-float4 (16 KB)
// window; thread handles t, t+256, t+512, t+768 (all within the window,
// all fully lane-coalesced). 4 loads + 4 stores in flight per thread;
// window stays dense (R4 showed far-split regresses, R6 showed 2x
// block-local wins). All 4 elements share j (256 % 32 == 0), s differs
// by 8 -> table reads are 4 nearby rows, L1/L2-friendly.

typedef float f32x4 __attribute__((ext_vector_type(4)));
typedef float f32x2 __attribute__((ext_vector_type(2)));

#define S_LEN 16384
#define DK    128
#define NF4_PER_ROW (DK / 4)              // 32 float4 per row
#define BLOCK 256
#define UNROLL 4

__global__ __launch_bounds__(BLOCK) void rope_f32_kernel(
    const f32x4* __restrict__ x,
    const f32x2* __restrict__ cos_tab,   // rows of 64 f32 = 32 float2
    const f32x2* __restrict__ sin_tab,
    const int*   __restrict__ tok_pos,
    f32x4*       __restrict__ out)
{
    const int base = blockIdx.x * (UNROLL * BLOCK) + threadIdx.x;

    int   t[UNROLL];
    f32x4 v[UNROLL];
    f32x2 c[UNROLL], sn[UNROLL];

#pragma unroll
    for (int u = 0; u < UNROLL; ++u) {
        t[u] = base + u * BLOCK;
        v[u] = x[t[u]];                       // 4 loads in flight
    }
#pragma unroll
    for (int u = 0; u < UNROLL; ++u) {
        const int j   = t[u] & (NF4_PER_ROW - 1);
        const int s   = (t[u] >> 5) & (S_LEN - 1);
        const int pos = tok_pos[s];
        c[u]  = cos_tab[pos * (DK / 4) + j];
        sn[u] = sin_tab[pos * (DK / 4) + j];
    }
#pragma unroll
    for (int u = 0; u < UNROLL; ++u) {
        f32x4 o;
        o.x = c[u].x * v[u].x - sn[u].x * v[u].y;
        o.y = sn[u].x * v[u].x + c[u].x * v[u].y;
        o.z = c[u].y * v[u].z - sn[u].y * v[u].w;
        o.w = sn[u].y * v[u].z + c[u].y * v[u].w;
        out[t[u]] = o;
    }
}

extern "C" void kernel_launch(void* const* d_in, const int* in_sizes, int n_in,
                              void* d_out, int out_size, void* d_ws, size_t ws_size,
                              hipStream_t stream) {
    const f32x4* x   = (const f32x4*)d_in[0];
    const f32x2* ct  = (const f32x2*)d_in[1];
    const f32x2* st  = (const f32x2*)d_in[2];
    const int*   tp  = (const int*)d_in[3];
    f32x4*       out = (f32x4*)d_out;

    const int n_f4  = out_size / 4;                 // 4,194,304
    const int grid  = n_f4 / (UNROLL * BLOCK);      // 4096

    rope_f32_kernel<<<grid, BLOCK, 0, stream>>>(x, ct, st, tp, out);
}

// Round 8
// 25.450 us; speedup vs baseline: 1.0145x; 1.0145x over previous
//
#include <hip/hip_runtime.h>

// RoPE: x (B=8, S=16384, D=128) f32, cos/sin tables (16384, 64) f32,
// token_positions (16384,) i32. Interleaved pair layout:
// out[2i]   = cos[i]*x[2i] - sin[i]*x[2i+1]
// out[2i+1] = sin[i]*x[2i] + cos[i]*x[2i+1]
//
// BEST MEASURED (R6, 25.21 us = ~5.66 TB/s = 90% of float4-copy ceiling).
// Block-local 2x MLP: each block owns a contiguous 512-float4 (8 KB)
// window; thread handles t and t+256 (4 KB apart -> same DRAM page
// neighborhood, both fully coalesced). Doubles in-flight loads/stores
// per thread WITHOUT fragmenting the block's memory front.
// Measured worse: nt-hints (26.9), far-split 2x (28.6), persistent
// grid-stride (27.2), block-local 4x (25.8).

typedef float f32x4 __attribute__((ext_vector_type(4)));
typedef float f32x2 __attribute__((ext_vector_type(2)));

#define S_LEN 16384
#define DK    128
#define NF4_PER_ROW (DK / 4)              // 32 float4 per row
#define BLOCK 256

__global__ __launch_bounds__(BLOCK) void rope_f32_kernel(
    const f32x4* __restrict__ x,
    const f32x2* __restrict__ cos_tab,   // rows of 64 f32 = 32 float2
    const f32x2* __restrict__ sin_tab,
    const int*   __restrict__ tok_pos,
    f32x4*       __restrict__ out)
{
    const int t0 = blockIdx.x * (2 * BLOCK) + threadIdx.x;
    const int t1 = t0 + BLOCK;

    const int j0 = t0 & (NF4_PER_ROW - 1);
    const int s0 = (t0 >> 5) & (S_LEN - 1);
    const int j1 = t1 & (NF4_PER_ROW - 1);
    const int s1 = (t1 >> 5) & (S_LEN - 1);

    const int pos0 = tok_pos[s0];
    const int pos1 = tok_pos[s1];

    const f32x4 v0 = x[t0];
    const f32x4 v1 = x[t1];
    const f32x2 c0  = cos_tab[pos0 * (DK / 4) + j0];
    const f32x2 sn0 = sin_tab[pos0 * (DK / 4) + j0];
    const f32x2 c1  = cos_tab[pos1 * (DK / 4) + j1];
    const f32x2 sn1 = sin_tab[pos1 * (DK / 4) + j1];

    f32x4 o0, o1;
    o0.x = c0.x * v0.x - sn0.x * v0.y;
    o0.y = sn0.x * v0.x + c0.x * v0.y;
    o0.z = c0.y * v0.z - sn0.y * v0.w;
    o0.w = sn0.y * v0.z + c0.y * v0.w;

    o1.x = c1.x * v1.x - sn1.x * v1.y;
    o1.y = sn1.x * v1.x + c1.x * v1.y;
    o1.z = c1.y * v1.z - sn1.y * v1.w;
    o1.w = sn1.y * v1.z + c1.y * v1.w;

    out[t0] = o0;
    out[t1] = o1;
}

extern "C" void kernel_launch(void* const* d_in, const int* in_sizes, int n_in,
                              void* d_out, int out_size, void* d_ws, size_t ws_size,
                              hipStream_t stream) {
    const f32x4* x   = (const f32x4*)d_in[0];
    const f32x2* ct  = (const f32x2*)d_in[1];
    const f32x2* st  = (const f32x2*)d_in[2];
    const int*   tp  = (const int*)d_in[3];
    f32x4*       out = (f32x4*)d_out;

    const int n_f4  = out_size / 4;                 // 4,194,304
    const int grid  = n_f4 / (2 * BLOCK);           // 8192

    rope_f32_kernel<<<grid, BLOCK, 0, stream>>>(x, ct, st, tp, out);
}